// Round 4
// baseline (578.579 us; speedup 1.0000x reference)
//
#include <hip/hip_runtime.h>
#include <stdint.h>

// Problem constants: B=4, T=512, S=256, V=50257.
#define DIM_B 4
#define DIM_T 512
#define DIM_S 256
#define DIM_V 50257
#define NROW   (DIM_B * DIM_T)            // 2048 rows
#define NCHUNK 25731584                   // NROW*DIM_V/4 (exact, %4==0)
#define NBMW   (NCHUNK / 32)              // 804112 bitmap words (exact)
#define HSZ    512                        // per-row hash slots (load <= 0.5)
#define HMSK   (HSZ - 1)

// Exact magic division by 50257 for e < 2^27:
// m = 175022247 = ceil(2^43/50257); m*d - 2^43 = 45271 <= 2^(43-27) -> exact.
__device__ __forceinline__ uint32_t div50257(uint32_t e) {
    return (uint32_t)(((uint64_t)e * 175022247ULL) >> 43);
}

// ---- K1: zero the global chunk-bitmap (3.2 MB in ws) ----
__global__ __launch_bounds__(256) void zero_bitmap_kernel(uint4* __restrict__ bm4) {
    const int n = NBMW / 4;               // 201028 (exact)
    const int stride = gridDim.x * blockDim.x;
    const uint4 z = make_uint4(0u, 0u, 0u, 0u);
    for (int i = blockIdx.x * blockDim.x + threadIdx.x; i < n; i += stride) bm4[i] = z;
}

// ---- K2: per-row LDS hash build + bitmap bits + dump to ws ----
__global__ __launch_bounds__(256) void build_kernel(
    const float* __restrict__ p_pos,      // [B,T,S]
    const int*   __restrict__ src,        // [B,S]
    int*         __restrict__ gk,         // [NROW*HSZ] hash keys
    float*       __restrict__ gv,         // [NROW*HSZ] hash vals
    unsigned*    __restrict__ gbm)        // [NBMW] flat chunk bitmap
{
    __shared__ int   hk[HSZ];
    __shared__ float hv[HSZ];
    const int row = blockIdx.x;           // row = b*T + t
    const int b   = row / DIM_T;
    const int tid = threadIdx.x;

    for (int i = tid; i < HSZ; i += 256) { hk[i] = -1; hv[i] = 0.0f; }
    __syncthreads();

    const int   v = src[b * DIM_S + tid];
    const float p = p_pos[(size_t)row * DIM_S + tid];
    int h = v & HMSK;
    while (true) {
        const int prev = atomicCAS(&hk[h], -1, v);
        if (prev == -1 || prev == v) { atomicAdd(&hv[h], p); break; }
        h = (h + 1) & HMSK;
    }
    const uint32_t flat  = (uint32_t)row * DIM_V + (uint32_t)v;
    const uint32_t chunk = flat >> 2;
    atomicOr(&gbm[chunk >> 5], 1u << (chunk & 31));
    __syncthreads();

    #pragma unroll
    for (int i = tid; i < HSZ; i += 256) {
        gk[row * HSZ + i] = hk[i];
        gv[row * HSZ + i] = hv[i];
    }
}

// ---- K3: flat grid-stride single-touch stream of the whole output ----
// Fill-identical global write front; flagged chunks (~2%) compose lanes from
// the L2-resident hash. Every output byte written exactly once.
__global__ __launch_bounds__(256) void stream_kernel(
    const int*      __restrict__ gk,
    const float*    __restrict__ gv,
    const unsigned* __restrict__ gbm,
    float4*         __restrict__ out4)
{
    const int stride = gridDim.x * blockDim.x;
    #pragma unroll 4
    for (int g = blockIdx.x * blockDim.x + threadIdx.x; g < NCHUNK; g += stride) {
        const unsigned w = gbm[g >> 5];
        float4 o = make_float4(0.0f, 0.0f, 0.0f, 0.0f);
        if ((w >> (g & 31)) & 1u) {        // ~2% of chunks
            float vals[4];
            const uint32_t e0 = (uint32_t)g << 2;
            #pragma unroll
            for (int j = 0; j < 4; ++j) {
                const uint32_t e = e0 + (uint32_t)j;
                const uint32_t r = div50257(e);
                const int col = (int)(e - r * (uint32_t)DIM_V);
                int h = col & HMSK;
                float val = 0.0f;
                while (true) {
                    const int k = gk[r * HSZ + h];
                    if (k == col) { val = gv[r * HSZ + h]; break; }
                    if (k == -1) break;
                    h = (h + 1) & HMSK;
                }
                vals[j] = val;
            }
            o = make_float4(vals[0], vals[1], vals[2], vals[3]);
        }
        out4[g] = o;
    }
}

extern "C" void kernel_launch(void* const* d_in, const int* in_sizes, int n_in,
                              void* d_out, int out_size, void* d_ws, size_t ws_size,
                              hipStream_t stream) {
    const float* p_pos = (const float*)d_in[0];   // [B,T,S]
    // d_in[1] = p_target_vocab — dead data (shape-only in the reference).
    const int*   src   = (const int*)d_in[2];     // [B,S]
    float*       out   = (float*)d_out;           // [B,T,V]

    // ws layout (all 4MB-aligned): keys 4MB | vals 4MB | bitmap 3.2MB
    int*      gk  = (int*)d_ws;
    float*    gv  = (float*)((char*)d_ws + (size_t)NROW * HSZ * 4);
    unsigned* gbm = (unsigned*)((char*)d_ws + 2 * (size_t)NROW * HSZ * 4);

    zero_bitmap_kernel<<<128, 256, 0, stream>>>((uint4*)gbm);
    build_kernel<<<NROW, DIM_S, 0, stream>>>(p_pos, src, gk, gv, gbm);
    stream_kernel<<<512, 256, 0, stream>>>(gk, gv, gbm, (float4*)out);
}

// Round 5
// 94.794 us; speedup vs baseline: 6.1035x; 6.1035x over previous
//
#include <hip/hip_runtime.h>

// Problem constants (from reference): B=4, T=512, S=256, V=50257.
#define DIM_B 4
#define DIM_T 512
#define DIM_S 256
#define DIM_V 50257
#define HSZ   512          // per-row LDS hash slots (<=256 entries -> load factor 0.5)
#define HMSK  (HSZ - 1)

// Patch kernel: one block per output row (b,t).
//  1. Build LDS hash v -> sum(p) over the row's 256 scatter entries
//     (open addressing, LDS CAS + LDS atomicAdd: exact duplicate handling).
//  2. Each occupied slot issues ONE plain 4B store out[row, v] = sum.
// No global atomics (no RMW fetch), no vectorized chunk composition (so no
// row-boundary chunk hazards), unique (row,v) per slot (no store collisions).
// The bulk zeroing is done beforehand by hipMemsetAsync (vendor fillBuffer,
// measured 6.7-6.9 TB/s on this chip); stream order guarantees patch-after-zero.
__global__ __launch_bounds__(256) void patch_kernel(
    const float* __restrict__ p_pos,   // [B, T, S]
    const int*   __restrict__ src,     // [B, S]  (int64 narrowed to int32)
    float*       __restrict__ out)     // [B, T, V]
{
    __shared__ int   hk[HSZ];
    __shared__ float hv[HSZ];

    const int row = blockIdx.x;        // row = b*T + t
    const int b   = row / DIM_T;
    const int tid = threadIdx.x;       // s index (S == blockDim.x == 256)

    for (int i = tid; i < HSZ; i += 256) { hk[i] = -1; hv[i] = 0.0f; }
    __syncthreads();

    const int   v = src[b * DIM_S + tid];
    const float p = p_pos[(size_t)row * DIM_S + tid];
    int h = v & HMSK;
    while (true) {
        const int prev = atomicCAS(&hk[h], -1, v);
        if (prev == -1 || prev == v) { atomicAdd(&hv[h], p); break; }
        h = (h + 1) & HMSK;
    }
    __syncthreads();

    float* __restrict__ row_ptr = out + (size_t)row * DIM_V;
    for (int i = tid; i < HSZ; i += 256) {
        const int k = hk[i];
        if (k >= 0) row_ptr[k] = hv[i];   // plain 4B store, unique address
    }
}

extern "C" void kernel_launch(void* const* d_in, const int* in_sizes, int n_in,
                              void* d_out, int out_size, void* d_ws, size_t ws_size,
                              hipStream_t stream) {
    const float* p_pos = (const float*)d_in[0];   // [B,T,S]
    // d_in[1] = p_target_vocab — dead data (shape-only in the reference).
    const int*   src   = (const int*)d_in[2];     // [B,S]
    float*       out   = (float*)d_out;           // [B,T,V]

    // Bulk zero via the vendor fill path (graph-captures as a memset node).
    hipMemsetAsync(d_out, 0, (size_t)out_size * sizeof(float), stream);

    // Scatter the 524,288 accumulated values on top.
    patch_kernel<<<DIM_B * DIM_T, DIM_S, 0, stream>>>(p_pos, src, out);
}